// Round 1
// baseline (891.335 us; speedup 1.0000x reference)
//
#include <hip/hip_runtime.h>
#include <hip/hip_cooperative_groups.h>
#include <math.h>

namespace cg = cooperative_groups;

namespace {
constexpr int Bx = 16;
constexpr int Cx = 256;
constexpr int Hx = 128;
constexpr int Wx = 128;
constexpr int PLANE = Hx * Wx;      // 16384 floats per (b,c) plane
constexpr int NPLANES = Bx * Cx;    // 4096
constexpr int SQ = 256;             // bottleneck dim
constexpr int C4 = 4 * Cx;          // 1024
constexpr int NBLK = 1024;          // cooperative grid: 4 blocks/CU * 256 CUs
constexpr int PPB = NPLANES / NBLK; // 4 planes per block per streaming phase
}

// ---------------------------------------------------------------------------
// Single persistent cooperative kernel.
//   P1: per-(b,c) quadrant sums (grid-stride, 4 planes/block) -> means (ws)
//   P2: z = mish(means @ Wr^T + br)      (16 blocks, 1 per batch)
//   P3: gate = sigmoid(z @ We^T + be)    (64 blocks, 4 per batch)
//   P4: out = t * gate, planes in REVERSE order so the tail of t that P1
//       left hot in the 256 MiB L3 is re-read before streaming writes
//       evict it.
// launch_bounds(256,4): forces <=128 VGPR -> >=4 blocks/CU -> 1024 blocks
// are guaranteed co-resident for grid.sync().
// ---------------------------------------------------------------------------
__global__ __launch_bounds__(256, 4) void fused(
    const float* __restrict__ t,
    const float* __restrict__ w_reduce,
    const float* __restrict__ b_reduce,
    const float* __restrict__ w_expand,
    const float* __restrict__ b_expand,
    float* __restrict__ out,
    float* __restrict__ ws) {
    float* means = ws;                  // Bx*C4 floats
    float* zbuf  = ws + Bx * C4;        // Bx*SQ floats
    float* gate  = zbuf + Bx * SQ;      // Bx*C4 floats

    cg::grid_group grid = cg::this_grid();
    const int tid = threadIdx.x;

    __shared__ __align__(16) float sh[C4];  // P2: means stage; P3: z stage
    __shared__ float red[4][4];             // P1: [quadrant][wave]

    // ---------------- P1: quadrant sums ----------------
    // float4 index v = tid + 256*i: row = v>>5 (top iff i<8),
    // col4 = tid&31 (left iff (tid>>4)&1 == 0).
    for (int p = 0; p < PPB; ++p) {
        const int plane = blockIdx.x * PPB + p;
        const float4* tp = (const float4*)(t + (size_t)plane * PLANE);

        float sTop = 0.f, sBot = 0.f;
#pragma unroll
        for (int i = 0; i < 8; ++i) {
            float4 d = tp[tid + 256 * i];
            sTop += (d.x + d.y) + (d.z + d.w);
        }
#pragma unroll
        for (int i = 8; i < 16; ++i) {
            float4 d = tp[tid + 256 * i];
            sBot += (d.x + d.y) + (d.z + d.w);
        }
        // Butterfly over xor masks {1,2,4,8,32}: reduces the 32 lanes of the
        // wave that share bit 4 (the column-side bit).
#pragma unroll
        for (int m = 1; m <= 8; m <<= 1) {
            sTop += __shfl_xor(sTop, m);
            sBot += __shfl_xor(sBot, m);
        }
        sTop += __shfl_xor(sTop, 32);
        sBot += __shfl_xor(sBot, 32);

        const int lane = tid & 63;
        const int wave = tid >> 6;
        const int qc = (tid >> 4) & 1;  // 0 = left half, 1 = right half
        if (lane == 0 || lane == 16) {
            red[qc][wave] = sTop;       // q0 / q1
            red[2 + qc][wave] = sBot;   // q2 / q3
        }
        __syncthreads();
        if (tid < 4) {
            const float s = red[tid][0] + red[tid][1] + red[tid][2] + red[tid][3];
            const int b = plane >> 8;
            const int c = plane & 255;
            means[b * C4 + tid * Cx + c] = s * (1.f / (64.f * 64.f));
        }
        __syncthreads();  // protect red[][] before next plane
    }
    grid.sync();

    // ---------------- P2: z = mish(means @ Wr^T + br) ----------------
    if (blockIdx.x < Bx) {
        const int b = blockIdx.x;
#pragma unroll
        for (int i = 0; i < 4; ++i)
            sh[tid + 256 * i] = means[b * C4 + tid + 256 * i];
        __syncthreads();

        float acc = b_reduce[tid];
        const float4* wr = (const float4*)(w_reduce + (size_t)tid * C4);
        const float4* m4 = (const float4*)sh;
#pragma unroll 8
        for (int k = 0; k < C4 / 4; ++k) {
            const float4 w = wr[k];
            const float4 m = m4[k];
            acc += m.x * w.x + m.y * w.y + m.z * w.z + m.w * w.w;
        }
        const float sp = (acc > 20.f) ? acc : log1pf(expf(acc));  // softplus
        zbuf[b * SQ + tid] = acc * tanhf(sp);                      // mish
    }
    grid.sync();

    // ---------------- P3: gate = sigmoid(z @ We^T + be) ----------------
    if (blockIdx.x < 4 * Bx) {
        const int b = blockIdx.x >> 2;
        const int j = ((blockIdx.x & 3) << 8) + tid;   // output index in [0,1024)
        sh[tid] = zbuf[b * SQ + tid];
        __syncthreads();

        float acc = b_expand[j];
        const float4* we = (const float4*)(w_expand + (size_t)j * SQ);
        const float4* z4 = (const float4*)sh;
#pragma unroll 8
        for (int k = 0; k < SQ / 4; ++k) {
            const float4 w = we[k];
            const float4 z = z4[k];
            acc += z.x * w.x + z.y * w.y + z.z * w.z + z.w * w.w;
        }
        gate[b * C4 + j] = 1.f / (1.f + expf(-acc));
    }
    grid.sync();

    // ---------------- P4: apply gates (reverse plane order) ----------------
    for (int p = 0; p < PPB; ++p) {
        const int plane = (NPLANES - 1) - (blockIdx.x * PPB + p);
        const int b = plane >> 8;
        const int c = plane & 255;

        const float g0 = gate[b * C4 + 0 * Cx + c];
        const float g1 = gate[b * C4 + 1 * Cx + c];
        const float g2 = gate[b * C4 + 2 * Cx + c];
        const float g3 = gate[b * C4 + 3 * Cx + c];
        const int qc = (tid >> 4) & 1;
        const float gTop = qc ? g1 : g0;
        const float gBot = qc ? g3 : g2;

        const float4* tp = (const float4*)(t + (size_t)plane * PLANE);
        float4* op = (float4*)(out + (size_t)plane * PLANE);
#pragma unroll
        for (int i = 0; i < 16; ++i) {
            float4 d = tp[tid + 256 * i];
            const float g = (i < 8) ? gTop : gBot;
            d.x *= g; d.y *= g; d.z *= g; d.w *= g;
            op[tid + 256 * i] = d;
        }
    }
}

extern "C" void kernel_launch(void* const* d_in, const int* in_sizes, int n_in,
                              void* d_out, int out_size, void* d_ws, size_t ws_size,
                              hipStream_t stream) {
    const float* t        = (const float*)d_in[0];
    const float* w_reduce = (const float*)d_in[1];
    const float* b_reduce = (const float*)d_in[2];
    const float* w_expand = (const float*)d_in[3];
    const float* b_expand = (const float*)d_in[4];
    float* out = (float*)d_out;
    float* ws  = (float*)d_ws;   // needs (16*1024 + 16*256 + 16*1024) floats = 144 KiB

    void* args[] = {(void*)&t, (void*)&w_reduce, (void*)&b_reduce,
                    (void*)&w_expand, (void*)&b_expand, (void*)&out, (void*)&ws};
    hipLaunchCooperativeKernel((const void*)fused, dim3(NBLK), dim3(256),
                               args, 0, stream);
}